// Round 8
// baseline (113.231 us; speedup 1.0000x reference)
//
#include <hip/hip_runtime.h>

typedef int   i32x4v __attribute__((ext_vector_type(4)));
typedef int   i32x8v __attribute__((ext_vector_type(8)));
typedef float f32x16 __attribute__((ext_vector_type(16)));

#define GLOBAL_AS(p) ((const __attribute__((address_space(1))) void*)(p))
#define LDS_AS(p)    ((__attribute__((address_space(3))) void*)(p))
#define BAR()     __builtin_amdgcn_s_barrier()
#define VMCNT(n)  asm volatile("s_waitcnt vmcnt(" #n ")" ::: "memory")

// ---------------- exp(x) -> fp8 e4m3, contiguous [M][K] ----------------
__global__ void expcvt_a8_kernel(const float* __restrict__ x,
                                 unsigned* __restrict__ y, size_t n8) {
  size_t tid0   = (size_t)blockIdx.x * blockDim.x + threadIdx.x;
  size_t stride = (size_t)gridDim.x * blockDim.x;
  const float4* x4 = (const float4*)x;
  for (size_t i = tid0; i < n8; i += stride) {
    float4 v0 = x4[2 * i], v1 = x4[2 * i + 1];
    int lo = 0, hi = 0;
    lo = __builtin_amdgcn_cvt_pk_fp8_f32(__expf(v0.x), __expf(v0.y), lo, false);
    lo = __builtin_amdgcn_cvt_pk_fp8_f32(__expf(v0.z), __expf(v0.w), lo, true);
    hi = __builtin_amdgcn_cvt_pk_fp8_f32(__expf(v1.x), __expf(v1.y), hi, false);
    hi = __builtin_amdgcn_cvt_pk_fp8_f32(__expf(v1.z), __expf(v1.w), hi, true);
    ((uint2*)y)[i] = make_uint2((unsigned)lo, (unsigned)hi);
  }
}

// ------------- exp(w) -> fp8 e4m3, transposed: Bt[n][d] -------------
__global__ void expcvt_wt8_kernel(const float* __restrict__ w,
                                  unsigned char* __restrict__ bt,
                                  int D, int O) {
  __shared__ unsigned char tile[32][33];
  int c0 = blockIdx.x * 32;   // O (col of w)
  int r0 = blockIdx.y * 32;   // D (row of w)
  int tx = threadIdx.x;       // 0..31
  int ty = threadIdx.y;       // 0..7
#pragma unroll
  for (int j = 0; j < 4; ++j) {
    int r = r0 + ty + j * 8;
    float e = __expf(w[(size_t)r * O + c0 + tx]);
    int p = __builtin_amdgcn_cvt_pk_fp8_f32(e, e, 0, false);
    tile[ty + j * 8][tx] = (unsigned char)(p & 0xFF);
  }
  __syncthreads();
  int t    = ty * 32 + tx;     // 0..255
  int orow = t >> 3;           // 0..31  (O index within tile)
  int b4   = (t & 7) * 4;      // 4-byte group along D
  unsigned u = (unsigned)tile[b4][orow] | ((unsigned)tile[b4 + 1][orow] << 8) |
               ((unsigned)tile[b4 + 2][orow] << 16) |
               ((unsigned)tile[b4 + 3][orow] << 24);
  *(unsigned*)(bt + (size_t)(c0 + orow) * D + r0 + b4) = u;
}

// ------------- 128x128 TLP-heavy MX-fp8 MFMA GEMM, log+bias epilogue -------------
// A  : [M][K] fp8 (exp_inputs)    Bt : [N][K] fp8 (exp_w transposed)
// out: [M][N] f32 = log(A@B) + bias[n]
// 256 thr = 4 waves (2 Mrow x 2 Ncol), per-wave C 64x64 = 2mb x 2nb of 32x32.
// BK = 64 B (one 32x32x64 MFMA K-depth). LDS: 2 bufs x (A 8KB + B 8KB) = 32KB
// -> 4 blocks/CU (LDS) and __launch_bounds__(256,4) caps VGPR at 128 for
// 16 waves/CU. Blocks free-run (no 8-wave lockstep) -> TLP hides the
// vmcnt(0) drain and ds_read latency (m148-structure, m114 overlap).
// Swizzle sigma_q(row) = ((row&6)<<3) ^ (row&16): involution on col bits 4-5;
// bank-distinct under contiguous-8 lane groups AND quad groups {l,l+16,l+32,l+48}.
// Applied on pre-swizzled global_load_lds SOURCE and on ds_read addresses.

#define FRG(P, OFF)                                                          \
  __builtin_shufflevector(*(const i32x4v*)((P) + (OFF) + c00),               \
                          *(const i32x4v*)((P) + (OFF) + c01),               \
                          0, 1, 2, 3, 4, 5, 6, 7)

__global__ __launch_bounds__(256, 4) void gemm_mx128_kernel(
    const unsigned char* __restrict__ A, const unsigned char* __restrict__ Bt,
    const float* __restrict__ bias, float* __restrict__ out,
    int M, int N, int K) {
  __shared__ char lds[32768];

  const int tid  = threadIdx.x;
  const int wid  = tid >> 6, lane = tid & 63;
  const int wr   = wid >> 1, wc = wid & 1;
  const int l31  = lane & 31, lk = lane >> 5;
  const int NTK  = K >> 6;       // 64B K-steps (32)
  const size_t Kb = (size_t)K;

  // XCD-aware bijective swizzle (gridDim.x % 8 == 0 here: 2048)
  const int cpx = gridDim.x >> 3;
  const int v   = (blockIdx.x & 7) * cpx + (blockIdx.x >> 3);
  const int nbn = N >> 7;        // 16
  const int bm  = v / nbn, bn = v % nbn;
  const int brow = bm << 7, bcol = bn << 7;

  // sigma_q(l31) = ((l31&6)<<3) ^ (l31&16); fragment col offsets
  const int swz = ((l31 & 6) << 3) ^ (l31 & 16);
  const int c00 = (lk * 32) ^ swz;
  const int c01 = c00 ^ 16;

  const char* pA = lds + (wr * 64 + l31) * 64;          // + mb*2048
  const char* pB = lds + 8192 + (wc * 64 + l31) * 64;   // + nb*2048

  // stage one K-step (A 8KB + B 8KB): 4 x global_load_lds(16B) per thread
  auto STAGE = [&](int t, int s) {
    const int tt = (t < NTK) ? t : NTK - 1;   // clamp keeps last iter uniform
    char* base = lds + s * 16384;
#pragma unroll
    for (int i = 0; i < 2; ++i) {
      const int o    = i * 4096 + tid * 16;
      const int row  = o >> 6;
      const int colb = (o & 63) ^ ((row & 6) << 3) ^ (row & 16);
      const char* gA = (const char*)A + (size_t)(brow + row) * Kb +
                       (size_t)tt * 64 + colb;
      const char* gB = (const char*)Bt + (size_t)(bcol + row) * Kb +
                       (size_t)tt * 64 + colb;
      __builtin_amdgcn_global_load_lds(GLOBAL_AS(gA),
          LDS_AS(base + i * 4096 + wid * 1024), 16, 0, 0);
      __builtin_amdgcn_global_load_lds(GLOBAL_AS(gB),
          LDS_AS(base + 8192 + i * 4096 + wid * 1024), 16, 0, 0);
    }
  };

  f32x16 acc[2][2];
#pragma unroll
  for (int m = 0; m < 2; ++m)
#pragma unroll
    for (int n = 0; n < 2; ++n) acc[m][n] = (f32x16)0.0f;

  STAGE(0, 0);
  VMCNT(0);
  BAR();

  for (int t = 0; t < NTK; ++t) {
    STAGE(t + 1, (t + 1) & 1);          // issue next-tile loads first
    const char* bufA = pA + (t & 1) * 16384;
    const char* bufB = pB + (t & 1) * 16384;
    i32x8v aF0 = FRG(bufA, 0);
    i32x8v aF1 = FRG(bufA, 2048);
    i32x8v bF0 = FRG(bufB, 0);
    i32x8v bF1 = FRG(bufB, 2048);
    acc[0][0] = __builtin_amdgcn_mfma_scale_f32_32x32x64_f8f6f4(
        aF0, bF0, acc[0][0], 0, 0, 0, 0x7F7F7F7F, 0, 0x7F7F7F7F);
    acc[0][1] = __builtin_amdgcn_mfma_scale_f32_32x32x64_f8f6f4(
        aF0, bF1, acc[0][1], 0, 0, 0, 0x7F7F7F7F, 0, 0x7F7F7F7F);
    acc[1][0] = __builtin_amdgcn_mfma_scale_f32_32x32x64_f8f6f4(
        aF1, bF0, acc[1][0], 0, 0, 0, 0x7F7F7F7F, 0, 0x7F7F7F7F);
    acc[1][1] = __builtin_amdgcn_mfma_scale_f32_32x32x64_f8f6f4(
        aF1, bF1, acc[1][1], 0, 0, 0, 0x7F7F7F7F, 0, 0x7F7F7F7F);
    VMCNT(0);   // next tile resident (one drain per K-step; TLP covers it)
    BAR();
  }

  // epilogue: out = log(acc) + bias, nontemporal (written once, never read)
  // 32x32 C/D layout: col = lane&31, row = (reg&3) + 8*(reg>>2) + 4*(lane>>5)
  const int col0 = bcol + wc * 64 + l31;
  const int row0 = brow + wr * 64 + lk * 4;
  const float bv0 = bias[col0], bv1 = bias[col0 + 32];
#pragma unroll
  for (int mb = 0; mb < 2; ++mb) {
#pragma unroll
    for (int rg = 0; rg < 16; ++rg) {
      const int row = row0 + mb * 32 + (rg & 3) + 8 * (rg >> 2);
      const size_t ro = (size_t)row * N + col0;
      __builtin_nontemporal_store(__logf(acc[mb][0][rg]) + bv0, &out[ro]);
      __builtin_nontemporal_store(__logf(acc[mb][1][rg]) + bv1, &out[ro + 32]);
    }
  }
}

extern "C" void kernel_launch(void* const* d_in, const int* in_sizes, int n_in,
                              void* d_out, int out_size, void* d_ws, size_t ws_size,
                              hipStream_t stream) {
  const float* inputs = (const float*)d_in[0];
  const float* w      = (const float*)d_in[1];
  const float* bias   = (const float*)d_in[2];
  float* out = (float*)d_out;

  const int O = in_sizes[2];                 // 2048
  const int D = in_sizes[1] / O;             // 2048
  const size_t MD = (size_t)in_sizes[0];     // M*D
  const int M = (int)(MD / (size_t)D);       // 16384

  unsigned char* A8  = (unsigned char*)d_ws;
  unsigned char* Bt8 = (unsigned char*)d_ws + MD;

  expcvt_a8_kernel<<<2048, 256, 0, stream>>>(inputs, (unsigned*)A8, MD / 8);

  dim3 tg(O / 32, D / 32);
  expcvt_wt8_kernel<<<tg, dim3(32, 8), 0, stream>>>(w, Bt8, D, O);

  dim3 grid((M / 128) * (O / 128));
  gemm_mx128_kernel<<<grid, 256, 0, stream>>>(A8, Bt8, bias, out, M, O, D);
}

// Round 9
// 101.620 us; speedup vs baseline: 1.1143x; 1.1143x over previous
//
#include <hip/hip_runtime.h>

typedef int   i32x4v __attribute__((ext_vector_type(4)));
typedef int   i32x8v __attribute__((ext_vector_type(8)));
typedef float f32x16 __attribute__((ext_vector_type(16)));

#define GLOBAL_AS(p) ((const __attribute__((address_space(1))) void*)(p))
#define LDS_AS(p)    ((__attribute__((address_space(3))) void*)(p))
#define BAR()     __builtin_amdgcn_s_barrier()
#define VMCNT(n)  asm volatile("s_waitcnt vmcnt(" #n ")" ::: "memory")

// ---------------- exp(x) -> fp8 e4m3, contiguous [M][K] ----------------
__global__ void expcvt_a8_kernel(const float* __restrict__ x,
                                 unsigned* __restrict__ y, size_t n8) {
  size_t tid0   = (size_t)blockIdx.x * blockDim.x + threadIdx.x;
  size_t stride = (size_t)gridDim.x * blockDim.x;
  const float4* x4 = (const float4*)x;
  for (size_t i = tid0; i < n8; i += stride) {
    float4 v0 = x4[2 * i], v1 = x4[2 * i + 1];
    int lo = 0, hi = 0;
    lo = __builtin_amdgcn_cvt_pk_fp8_f32(__expf(v0.x), __expf(v0.y), lo, false);
    lo = __builtin_amdgcn_cvt_pk_fp8_f32(__expf(v0.z), __expf(v0.w), lo, true);
    hi = __builtin_amdgcn_cvt_pk_fp8_f32(__expf(v1.x), __expf(v1.y), hi, false);
    hi = __builtin_amdgcn_cvt_pk_fp8_f32(__expf(v1.z), __expf(v1.w), hi, true);
    ((uint2*)y)[i] = make_uint2((unsigned)lo, (unsigned)hi);
  }
}

// ------------- exp(w) -> fp8 e4m3, transposed: Bt[n][d] -------------
__global__ void expcvt_wt8_kernel(const float* __restrict__ w,
                                  unsigned char* __restrict__ bt,
                                  int D, int O) {
  __shared__ unsigned char tile[32][33];
  int c0 = blockIdx.x * 32;   // O (col of w)
  int r0 = blockIdx.y * 32;   // D (row of w)
  int tx = threadIdx.x;       // 0..31
  int ty = threadIdx.y;       // 0..7
#pragma unroll
  for (int j = 0; j < 4; ++j) {
    int r = r0 + ty + j * 8;
    float e = __expf(w[(size_t)r * O + c0 + tx]);
    int p = __builtin_amdgcn_cvt_pk_fp8_f32(e, e, 0, false);
    tile[ty + j * 8][tx] = (unsigned char)(p & 0xFF);
  }
  __syncthreads();
  int t    = ty * 32 + tx;     // 0..255
  int orow = t >> 3;           // 0..31  (O index within tile)
  int b4   = (t & 7) * 4;      // 4-byte group along D
  unsigned u = (unsigned)tile[b4][orow] | ((unsigned)tile[b4 + 1][orow] << 8) |
               ((unsigned)tile[b4 + 2][orow] << 16) |
               ((unsigned)tile[b4 + 3][orow] << 24);
  *(unsigned*)(bt + (size_t)(c0 + orow) * D + r0 + b4) = u;
}

// ------- 128x256 3-buffer MX-fp8 MFMA GEMM (counted vmcnt), log+bias epilogue -------
// A  : [M][K] fp8 (exp_inputs)    Bt : [N][K] fp8 (exp_w transposed)
// out: [M][N] f32 = log(A@B) + bias[n]
// 256 thr = 4 waves (1 Mrow x 4 Ncol); wave C-tile 128x64 = 4mb x 2nb of 32x32
// (128 acc regs; intensity 1.5 ds_read_b128 per MFMA vs 2.0 in the 64x64 tile).
// BK = 64 B. LDS = 3 buffers x (A 8KB + B 16KB) = 72 KB -> 2 blocks/CU
// (__launch_bounds__(256,2), ~210 regs/wave).
// Pipeline: at iter t stage buf[t+2]; consume buf[t] (staged a FULL iteration
// earlier); vmcnt(6) at iter end retires buf[t+1]'s 6 loads, keeps buf[t+2]'s
// 6 in flight -> no memory-latency on the critical path, no full drains.
// Swizzle sigma_q(row) = ((row&6)<<3) ^ (row&16): proven-zero conflicts (r8).
// Applied on pre-swizzled global_load_lds SOURCE and on ds_read addresses.

#define FRG(P, OFF)                                                          \
  __builtin_shufflevector(*(const i32x4v*)((P) + (OFF) + c00),               \
                          *(const i32x4v*)((P) + (OFF) + c01),               \
                          0, 1, 2, 3, 4, 5, 6, 7)

#define MFMA1(MB, NB, BF)                                                    \
  acc[MB][NB] = __builtin_amdgcn_mfma_scale_f32_32x32x64_f8f6f4(             \
      aF[MB], BF, acc[MB][NB], 0, 0, 0, 0x7F7F7F7F, 0, 0x7F7F7F7F);

__global__ __launch_bounds__(256, 2) void gemm_mxA_kernel(
    const unsigned char* __restrict__ A, const unsigned char* __restrict__ Bt,
    const float* __restrict__ bias, float* __restrict__ out,
    int M, int N, int K) {
  __shared__ char lds[73728];           // 3 x 24 KB

  const int tid  = threadIdx.x;
  const int wid  = tid >> 6, lane = tid & 63;
  const int l31  = lane & 31, lk = lane >> 5;
  const int NTK  = K >> 6;              // 64B K-steps (32)
  const size_t Kb = (size_t)K;

  // XCD-aware bijective swizzle (gridDim.x % 8 == 0 here: 1024)
  const int cpx = gridDim.x >> 3;
  const int v   = (blockIdx.x & 7) * cpx + (blockIdx.x >> 3);
  const int nbn = N >> 8;               // 256-wide N blocks (8)
  const int bm  = v / nbn, bn = v % nbn;
  const int brow = bm << 7, bcol = bn << 8;

  // sigma_q fragment col offsets (16B-granular; zero-conflict per round 8)
  const int swz = ((l31 & 6) << 3) ^ (l31 & 16);
  const int c00 = (lk * 32) ^ swz;
  const int c01 = c00 ^ 16;

  // per-thread staging source base addresses (koff added per iteration)
  const int oA  = tid * 16;             // A: 2 loads, o = i*4096 + tid*16
  const char* gA[2];
  const char* gB[4];
#pragma unroll
  for (int i = 0; i < 2; ++i) {
    const int o = i * 4096 + oA, row = o >> 6;
    const int colb = (o & 63) ^ ((row & 6) << 3) ^ (row & 16);
    gA[i] = (const char*)A + (size_t)(brow + row) * Kb + colb;
  }
#pragma unroll
  for (int i = 0; i < 4; ++i) {
    const int o = i * 4096 + oA, row = o >> 6;
    const int colb = (o & 63) ^ ((row & 6) << 3) ^ (row & 16);
    gB[i] = (const char*)Bt + (size_t)(bcol + row) * Kb + colb;
  }

  // stage one K-step into buffer s: A 8KB (2 loads) + B 16KB (4 loads)
  auto STAGE = [&](int koff, int s) {
    char* base = lds + s * 24576;
#pragma unroll
    for (int i = 0; i < 2; ++i)
      __builtin_amdgcn_global_load_lds(GLOBAL_AS(gA[i] + koff),
          LDS_AS(base + i * 4096 + wid * 1024), 16, 0, 0);
#pragma unroll
    for (int i = 0; i < 4; ++i)
      __builtin_amdgcn_global_load_lds(GLOBAL_AS(gB[i] + koff),
          LDS_AS(base + 8192 + i * 4096 + wid * 1024), 16, 0, 0);
  };

  f32x16 acc[4][2];
#pragma unroll
  for (int m = 0; m < 4; ++m)
#pragma unroll
    for (int n = 0; n < 2; ++n) acc[m][n] = (f32x16)0.0f;

  // read bases (buffer offset s*24576 added per iteration)
  const char* rdA = lds + l31 * 64;                  // + mb*2048
  const char* rdB = lds + 8192 + (wid * 64 + l31) * 64;  // + nb*2048

  // prologue: stage t=0 -> buf0, t=1 -> buf1; wait for buf0 (keep 6 in flight)
  STAGE(0, 0);
  STAGE(64, 1);
  VMCNT(6);
  BAR();

  int s0 = 0, s1 = 1, s2 = 2;
  for (int t = 0; t < NTK; ++t) {
    const int tt = (t + 2 < NTK) ? (t + 2) : (NTK - 1);
    STAGE(tt << 6, s2);

    const char* bufA = rdA + s0 * 24576;
    const char* bufB = rdB + s0 * 24576;
    i32x8v aF[4], bF0, bF1;
#pragma unroll
    for (int mb = 0; mb < 4; ++mb) aF[mb] = FRG(bufA, mb * 2048);
    bF0 = FRG(bufB, 0);
    bF1 = FRG(bufB, 2048);
    MFMA1(0, 0, bF0) MFMA1(1, 0, bF0) MFMA1(2, 0, bF0) MFMA1(3, 0, bF0)
    MFMA1(0, 1, bF1) MFMA1(1, 1, bF1) MFMA1(2, 1, bF1) MFMA1(3, 1, bF1)

    VMCNT(6);   // retire buf[t+1]'s loads; buf[t+2]'s 6 stay in flight
    BAR();
    const int sw = s0; s0 = s1; s1 = s2; s2 = sw;
  }

  // epilogue: out = log(acc) + bias, nontemporal (written once, never read)
  // 32x32 C/D layout: col = lane&31, row = (reg&3) + 8*(reg>>2) + 4*(lane>>5)
  const int col0 = bcol + wid * 64 + l31;
  const int row0 = brow + lk * 4;
  const float bv0 = bias[col0], bv1 = bias[col0 + 32];
#pragma unroll
  for (int mb = 0; mb < 4; ++mb) {
#pragma unroll
    for (int rg = 0; rg < 16; ++rg) {
      const int row = row0 + mb * 32 + (rg & 3) + 8 * (rg >> 2);
      const size_t ro = (size_t)row * N + col0;
      __builtin_nontemporal_store(__logf(acc[mb][0][rg]) + bv0, &out[ro]);
      __builtin_nontemporal_store(__logf(acc[mb][1][rg]) + bv1, &out[ro + 32]);
    }
  }
}

extern "C" void kernel_launch(void* const* d_in, const int* in_sizes, int n_in,
                              void* d_out, int out_size, void* d_ws, size_t ws_size,
                              hipStream_t stream) {
  const float* inputs = (const float*)d_in[0];
  const float* w      = (const float*)d_in[1];
  const float* bias   = (const float*)d_in[2];
  float* out = (float*)d_out;

  const int O = in_sizes[2];                 // 2048
  const int D = in_sizes[1] / O;             // 2048
  const size_t MD = (size_t)in_sizes[0];     // M*D
  const int M = (int)(MD / (size_t)D);       // 16384

  unsigned char* A8  = (unsigned char*)d_ws;
  unsigned char* Bt8 = (unsigned char*)d_ws + MD;

  expcvt_a8_kernel<<<2048, 256, 0, stream>>>(inputs, (unsigned*)A8, MD / 8);

  dim3 tg(O / 32, D / 32);
  expcvt_wt8_kernel<<<tg, dim3(32, 8), 0, stream>>>(w, Bt8, D, O);

  dim3 grid((M / 128) * (O / 256));
  gemm_mxA_kernel<<<grid, 256, 0, stream>>>(A8, Bt8, bias, out, M, O, D);
}